// Round 14
// baseline (275.620 us; speedup 1.0000x reference)
//
#include <hip/hip_runtime.h>
#include <hip/hip_bf16.h>
#include <stdint.h>

typedef __bf16  bf16x8 __attribute__((ext_vector_type(8)));
typedef __bf16  bf16x4 __attribute__((ext_vector_type(4)));
typedef float   f32x4  __attribute__((ext_vector_type(4)));
typedef uint32_t u32x4 __attribute__((ext_vector_type(4)));

#define S     2048
#define D     128
#define THR2  11.5415603f   // 8 * log2(e)

__device__ __forceinline__ uint32_t cvt_pk(float lo, float hi2) {
    uint32_t u;
    asm("v_cvt_pk_bf16_f32 %0, %1, %2" : "=v"(u) : "v"(lo), "v"(hi2));
    return u;
}
__device__ __forceinline__ float exp2fast(float x) {
    return __builtin_amdgcn_exp2f(x);
}

// ================= kernel A: pack K->bf16, V->bf16 transposed =================
__global__ __launch_bounds__(256) void pack_kv(
    const float* __restrict__ K, const float* __restrict__ V,
    __bf16* __restrict__ Kb, __bf16* __restrict__ Vt)
{
    const int bh = blockIdx.x, tile = blockIdx.y, kind = blockIdx.z;
    const int tid = threadIdx.x;
    const int s0 = tile * 64;

    if (kind == 0) {           // K: straight convert, coalesced both sides
        const float* src = K  + ((size_t)bh * S + s0) * D;
        __bf16*      dst = Kb + ((size_t)bh * S + s0) * D;
        #pragma unroll
        for (int it = 0; it < 8; ++it) {
            const int id  = it * 256 + tid;
            const int off = (id >> 5) * D + (id & 31) * 4;
            float4 v = *reinterpret_cast<const float4*>(src + off);
            bf16x4 b;
            b[0]=(__bf16)v.x; b[1]=(__bf16)v.y; b[2]=(__bf16)v.z; b[3]=(__bf16)v.w;
            *reinterpret_cast<bf16x4*>(dst + off) = b;
        }
    } else {                   // V: LDS tile transpose -> Vt[bh][d][s]
        __shared__ __bf16 lds[64][136];        // +8 pad: stride 272B
        const float* src = V + ((size_t)bh * S + s0) * D;
        #pragma unroll
        for (int it = 0; it < 8; ++it) {
            const int id  = it * 256 + tid;
            const int row = id >> 5, c4 = (id & 31) * 4;
            float4 v = *reinterpret_cast<const float4*>(src + row * D + c4);
            bf16x4 b;
            b[0]=(__bf16)v.x; b[1]=(__bf16)v.y; b[2]=(__bf16)v.z; b[3]=(__bf16)v.w;
            *reinterpret_cast<bf16x4*>(&lds[row][c4]) = b;
        }
        __syncthreads();
        const int d = tid >> 1, sh = (tid & 1) * 32;
        __bf16* dst = Vt + (size_t)bh * D * S + (size_t)d * S + s0 + sh;
        bf16x8 o[4];
        #pragma unroll
        for (int k = 0; k < 32; ++k) o[k >> 3][k & 7] = lds[sh + k][d];
        #pragma unroll
        for (int kk = 0; kk < 4; ++kk)
            *reinterpret_cast<bf16x8*>(dst + kk * 8) = o[kk];
    }
}

// ================= kernel B: barrier-free attention core =================
// wave u handles q-tile j1 = 64+u then j2 = 63-u  (65 kv-tiles total, uniform)
__global__ __launch_bounds__(256) void attn_core(
    const float* __restrict__ Q, const __bf16* __restrict__ Kb,
    const __bf16* __restrict__ Vt, float* __restrict__ O)
{
    const int bh = blockIdx.x;
    const int tid  = threadIdx.x;
    const int u    = blockIdx.y * 4 + (tid >> 6);   // 0..63
    const int lane = tid & 63;
    const int r    = lane & 15;
    const int g    = lane >> 4;

    const float* Qh = Q  + (size_t)bh * S * D;
    const __bf16* Kh = Kb + (size_t)bh * S * D;
    const __bf16* Vh = Vt + (size_t)bh * D * S;
    float*       Oh = O  + (size_t)bh * S * D;

    const float scale = 0.08838834764831845f * 1.4426950408889634f;
    const f32x4 vzero = {0.f, 0.f, 0.f, 0.f};

    #pragma unroll 1
    for (int pass = 0; pass < 2; ++pass) {
        const int j  = pass ? (63 - u) : (64 + u);
        const int q0 = j * 16;
        const int n_tiles = ((q0 + 15) >> 5) + 1;

        // Q fragments (B operand): col = q0+r, k = kb*32 + g*8 + e
        bf16x8 qfrag[4];
        {
            const float4* qp = reinterpret_cast<const float4*>(
                Qh + (size_t)(q0 + r) * D + g * 8);
            #pragma unroll
            for (int kb = 0; kb < 4; ++kb) {
                float4 a = qp[kb*8 + 0];
                float4 b = qp[kb*8 + 1];
                a.x*=scale; a.y*=scale; a.z*=scale; a.w*=scale;
                b.x*=scale; b.y*=scale; b.z*=scale; b.w*=scale;
                bf16x8 f;
                f[0]=(__bf16)a.x; f[1]=(__bf16)a.y; f[2]=(__bf16)a.z; f[3]=(__bf16)a.w;
                f[4]=(__bf16)b.x; f[5]=(__bf16)b.y; f[6]=(__bf16)b.z; f[7]=(__bf16)b.w;
                qfrag[kb] = f;
            }
        }

        f32x4 acc_o[8];
        #pragma unroll
        for (int i = 0; i < 8; ++i) acc_o[i] = vzero;
        float m_run = -1e30f, l_run = 0.f;

        for (int t = 0; t < n_tiles; ++t) {
            const int kv0 = t * 32;
            const bool alive1 = (kv0 + 16 <= q0 + 15);

            // ---- QK: A = K rows (direct 16B bf16 loads) ----
            f32x4 st[2] = {vzero, vzero};
            __builtin_amdgcn_s_setprio(1);
            #pragma unroll
            for (int tt = 0; tt < 2; ++tt) {
                if (tt == 1 && !alive1) break;
                const __bf16* krow = Kh + (size_t)(kv0 + tt*16 + r) * D + g * 8;
                #pragma unroll
                for (int kb = 0; kb < 4; ++kb) {
                    bf16x8 kf = *reinterpret_cast<const bf16x8*>(krow + kb * 32);
                    st[tt] = __builtin_amdgcn_mfma_f32_16x16x32_bf16(
                        kf, qfrag[kb], st[tt], 0, 0, 0);
                }
            }
            __builtin_amdgcn_s_setprio(0);

            // ---- mask + in-register online softmax (exp2 domain) ----
            const int q = q0 + r;
            float pmax = -1e30f;
            #pragma unroll
            for (int tt = 0; tt < 2; ++tt) {
                if (tt == 1 && !alive1) break;
                if (kv0 + tt*16 + 15 > q0) {
                    #pragma unroll
                    for (int jj = 0; jj < 4; ++jj)
                        if (kv0 + tt*16 + 4*g + jj > q) st[tt][jj] = -1e30f;
                }
                #pragma unroll
                for (int jj = 0; jj < 4; ++jj) pmax = fmaxf(pmax, st[tt][jj]);
            }
            pmax = fmaxf(pmax, __shfl_xor(pmax, 16));
            pmax = fmaxf(pmax, __shfl_xor(pmax, 32));

            if (__any(pmax > m_run + THR2)) {        // rare (defer-max)
                const float m_new = fmaxf(m_run, pmax);
                const float corr  = exp2fast(m_run - m_new);
                l_run *= corr; m_run = m_new;
                #pragma unroll
                for (int reg = 0; reg < 4; ++reg) {
                    const float cr = __shfl(corr, 4*g + reg);
                    #pragma unroll
                    for (int dt = 0; dt < 8; ++dt) acc_o[dt][reg] *= cr;
                }
            }

            float rowsum = 0.f;
            #pragma unroll
            for (int tt = 0; tt < 2; ++tt) {
                if (tt == 1 && !alive1) break;
                #pragma unroll
                for (int jj = 0; jj < 4; ++jj) {
                    const float p = exp2fast(st[tt][jj] - m_run);
                    st[tt][jj] = p;
                    rowsum += p;
                }
            }
            rowsum += __shfl_xor(rowsum, 16);
            rowsum += __shfl_xor(rowsum, 32);
            l_run += rowsum;

            // ---- P redistribute to A-fragment (k = g*8 + e) ----
            const uint32_t p00 = cvt_pk(st[0][0], st[0][1]);
            const uint32_t p01 = cvt_pk(st[0][2], st[0][3]);
            const uint32_t p10 = alive1 ? cvt_pk(st[1][0], st[1][1]) : 0u;
            const uint32_t p11 = alive1 ? cvt_pk(st[1][2], st[1][3]) : 0u;
            const int sA = r + ((2 * (g & 1)) << 4);
            const int sB = r + ((2 * (g & 1) + 1) << 4);
            u32x4 words;
            {
                const uint32_t lo0 = (uint32_t)__shfl((int)p00, sA);
                const uint32_t hi0 = (uint32_t)__shfl((int)p10, sA);
                const uint32_t lo1 = (uint32_t)__shfl((int)p01, sA);
                const uint32_t hi1 = (uint32_t)__shfl((int)p11, sA);
                const uint32_t lo2 = (uint32_t)__shfl((int)p00, sB);
                const uint32_t hi2 = (uint32_t)__shfl((int)p10, sB);
                const uint32_t lo3 = (uint32_t)__shfl((int)p01, sB);
                const uint32_t hi3 = (uint32_t)__shfl((int)p11, sB);
                words[0] = (g & 2) ? hi0 : lo0;
                words[1] = (g & 2) ? hi1 : lo1;
                words[2] = (g & 2) ? hi2 : lo2;
                words[3] = (g & 2) ? hi3 : lo3;
            }
            const bf16x8 pa = __builtin_bit_cast(bf16x8, words);

            // ---- PV: B = Vt[d][kv] (direct 16B bf16 loads) ----
            __builtin_amdgcn_s_setprio(1);
            #pragma unroll
            for (int dt = 0; dt < 8; ++dt) {
                bf16x8 vf = *reinterpret_cast<const bf16x8*>(
                    Vh + (size_t)(dt*16 + r) * S + kv0 + g * 8);
                acc_o[dt] = __builtin_amdgcn_mfma_f32_16x16x32_bf16(
                    pa, vf, acc_o[dt], 0, 0, 0);
            }
            __builtin_amdgcn_s_setprio(0);
        }

        // ---- epilogue ----
        const float inv = 1.0f / l_run;
        #pragma unroll
        for (int reg = 0; reg < 4; ++reg) {
            const float iv = __shfl(inv, 4*g + reg);
            float* orow = Oh + (size_t)(q0 + 4*g + reg) * D + r;
            #pragma unroll
            for (int dt = 0; dt < 8; ++dt)
                orow[dt * 16] = acc_o[dt][reg] * iv;
        }
    }
}

// ================= fallback (R11 structure) if workspace too small ==========
__global__ __launch_bounds__(256, 3) void attn_fallback(
    const float* __restrict__ Q, const float* __restrict__ K,
    const float* __restrict__ V, float* __restrict__ O)
{
    const int bh = blockIdx.x;
    const int qt = 31 - blockIdx.y;
    const int tid  = threadIdx.x;
    const int w    = tid >> 6;
    const int lane = tid & 63;
    const int r    = lane & 15;
    const int g    = lane >> 4;

    const size_t head_off = (size_t)bh * S * D;
    const float* Qh = Q + head_off;
    const float* Kh = K + head_off;
    const float* Vh = V + head_off;
    float*       Oh = O + head_off;

    const int q0w = qt * 64 + w * 16;
    __shared__ __bf16 K_sh [2][32 * D];
    __shared__ __bf16 Vt_sh[2][D * 40];
    const float scale = 0.08838834764831845f * 1.4426950408889634f;

    bf16x8 qfrag[4];
    {
        const float4* qp = reinterpret_cast<const float4*>(
            Qh + (size_t)(q0w + r) * D + g * 8);
        #pragma unroll
        for (int kb = 0; kb < 4; ++kb) {
            float4 a = qp[kb*8], b = qp[kb*8 + 1];
            a.x*=scale; a.y*=scale; a.z*=scale; a.w*=scale;
            b.x*=scale; b.y*=scale; b.z*=scale; b.w*=scale;
            bf16x8 f;
            f[0]=(__bf16)a.x; f[1]=(__bf16)a.y; f[2]=(__bf16)a.z; f[3]=(__bf16)a.w;
            f[4]=(__bf16)b.x; f[5]=(__bf16)b.y; f[6]=(__bf16)b.z; f[7]=(__bf16)b.w;
            qfrag[kb] = f;
        }
    }
    float4 kreg[4], vreg[4];
    const int c4 = tid & 31, kvq = tid >> 5;
    auto issue_loads = [&](int kv0) {
        #pragma unroll
        for (int it = 0; it < 4; ++it)
            kreg[it] = *reinterpret_cast<const float4*>(
                Kh + (size_t)(kv0 + ((it*256+tid)>>5)) * D + c4 * 4);
        #pragma unroll
        for (int kr = 0; kr < 4; ++kr)
            vreg[kr] = *reinterpret_cast<const float4*>(
                Vh + (size_t)(kv0 + kvq*4 + kr) * D + c4 * 4);
    };
    auto write_tiles = [&](int buf) {
        char* Kb2 = reinterpret_cast<char*>(K_sh[buf]);
        char* Vtb = reinterpret_cast<char*>(Vt_sh[buf]);
        #pragma unroll
        for (int it = 0; it < 4; ++it) {
            const int row = (it*256+tid) >> 5;
            bf16x4 k4;
            k4[0]=(__bf16)kreg[it].x; k4[1]=(__bf16)kreg[it].y;
            k4[2]=(__bf16)kreg[it].z; k4[3]=(__bf16)kreg[it].w;
            *reinterpret_cast<bf16x4*>(Kb2 + row*256 + ((c4*8) ^ ((row&15)<<4))) = k4;
        }
        #pragma unroll
        for (int j = 0; j < 4; ++j) {
            const int d = c4*4 + j;
            bf16x4 v4;
            #pragma unroll
            for (int kr = 0; kr < 4; ++kr) v4[kr] = (__bf16)((&vreg[kr].x)[j]);
            *reinterpret_cast<bf16x4*>(Vtb + d*80 + ((kvq ^ ((d>>2)&6))*8)) = v4;
        }
    };
    const f32x4 vzero = {0.f,0.f,0.f,0.f};
    f32x4 acc_o[8];
    #pragma unroll
    for (int i = 0; i < 8; ++i) acc_o[i] = vzero;
    float m_run = -1e30f, l_run = 0.f;
    const int n_iter = 2*qt + 2, my_max = (q0w + 15) >> 5;
    auto do_qk = [&](f32x4* st, int t, int kb_buf) {
        char* Kb2 = reinterpret_cast<char*>(K_sh[kb_buf]);
        const bool a1 = (t*32 + 16 <= q0w + 15);
        #pragma unroll
        for (int tt = 0; tt < 2; ++tt) {
            st[tt] = vzero;
            if (tt == 1 && !a1) break;
            const int row = tt*16 + r;
            #pragma unroll
            for (int kb = 0; kb < 4; ++kb) {
                bf16x8 kf = *reinterpret_cast<const bf16x8*>(
                    Kb2 + row*256 + ((kb*64 + g*16) ^ ((row&15)<<4)));
                st[tt] = __builtin_amdgcn_mfma_f32_16x16x32_bf16(
                    kf, qfrag[kb], st[tt], 0, 0, 0);
            }
        }
    };
    auto process = [&](f32x4* st, int t, int vt_buf) {
        const int kv0 = t*32;
        char* Vtb = reinterpret_cast<char*>(Vt_sh[vt_buf]);
        const bool alive1 = (kv0 + 16 <= q0w + 15);
        const int q = q0w + r;
        float pmax = -1e30f;
        #pragma unroll
        for (int tt = 0; tt < 2; ++tt) {
            if (tt == 1 && !alive1) break;
            if (kv0 + tt*16 + 15 > q0w)
                #pragma unroll
                for (int jj = 0; jj < 4; ++jj)
                    if (kv0 + tt*16 + 4*g + jj > q) st[tt][jj] = -1e30f;
            #pragma unroll
            for (int jj = 0; jj < 4; ++jj) pmax = fmaxf(pmax, st[tt][jj]);
        }
        pmax = fmaxf(pmax, __shfl_xor(pmax, 16));
        pmax = fmaxf(pmax, __shfl_xor(pmax, 32));
        if (__any(pmax > m_run + THR2)) {
            const float m_new = fmaxf(m_run, pmax);
            const float corr = exp2fast(m_run - m_new);
            l_run *= corr; m_run = m_new;
            #pragma unroll
            for (int reg = 0; reg < 4; ++reg) {
                const float cr = __shfl(corr, 4*g + reg);
                #pragma unroll
                for (int dt = 0; dt < 8; ++dt) acc_o[dt][reg] *= cr;
            }
        }
        float rowsum = 0.f;
        #pragma unroll
        for (int tt = 0; tt < 2; ++tt) {
            if (tt == 1 && !alive1) break;
            #pragma unroll
            for (int jj = 0; jj < 4; ++jj) {
                const float p = exp2fast(st[tt][jj] - m_run);
                st[tt][jj] = p; rowsum += p;
            }
        }
        rowsum += __shfl_xor(rowsum, 16);
        rowsum += __shfl_xor(rowsum, 32);
        l_run += rowsum;
        const uint32_t p00 = cvt_pk(st[0][0], st[0][1]);
        const uint32_t p01 = cvt_pk(st[0][2], st[0][3]);
        const uint32_t p10 = alive1 ? cvt_pk(st[1][0], st[1][1]) : 0u;
        const uint32_t p11 = alive1 ? cvt_pk(st[1][2], st[1][3]) : 0u;
        const int sA = r + ((2*(g&1)) << 4), sB = r + ((2*(g&1)+1) << 4);
        u32x4 words;
        {
            const uint32_t lo0=(uint32_t)__shfl((int)p00,sA), hi0=(uint32_t)__shfl((int)p10,sA);
            const uint32_t lo1=(uint32_t)__shfl((int)p01,sA), hi1=(uint32_t)__shfl((int)p11,sA);
            const uint32_t lo2=(uint32_t)__shfl((int)p00,sB), hi2=(uint32_t)__shfl((int)p10,sB);
            const uint32_t lo3=(uint32_t)__shfl((int)p01,sB), hi3=(uint32_t)__shfl((int)p11,sB);
            words[0]=(g&2)?hi0:lo0; words[1]=(g&2)?hi1:lo1;
            words[2]=(g&2)?hi2:lo2; words[3]=(g&2)?hi3:lo3;
        }
        const bf16x8 pa = __builtin_bit_cast(bf16x8, words);
        #pragma unroll
        for (int dt = 0; dt < 8; ++dt) {
            const int d = dt*16 + r;
            bf16x8 vf = *reinterpret_cast<const bf16x8*>(
                Vtb + d*80 + (((2*g) ^ ((d>>2)&6))*8));
            acc_o[dt] = __builtin_amdgcn_mfma_f32_16x16x32_bf16(
                pa, vf, acc_o[dt], 0, 0, 0);
        }
    };
    issue_loads(0); write_tiles(0);
    __syncthreads();
    issue_loads(32);
    f32x4 stA[2] = {vzero, vzero}, stB[2] = {vzero, vzero};
    do_qk(stA, 0, 0);
    write_tiles(1);
    for (int i = 0; i < n_iter; i += 2) {
        __syncthreads();
        if (i + 2 < n_iter) issue_loads((i + 2) * 32);
        if (i + 1 <= my_max) do_qk(stB, i + 1, 1);
        if (i     <= my_max) process(stA, i, 0);
        __syncthreads();
        if (i + 2 < n_iter) write_tiles(0);
        __syncthreads();
        if (i + 3 < n_iter) issue_loads((i + 3) * 32);
        if (i + 2 <= my_max) do_qk(stA, i + 2, 0);
        if (i + 1 <= my_max) process(stB, i + 1, 1);
        __syncthreads();
        if (i + 3 < n_iter) write_tiles(1);
    }
    const float inv = 1.0f / l_run;
    #pragma unroll
    for (int reg = 0; reg < 4; ++reg) {
        const float iv = __shfl(inv, 4*g + reg);
        float* orow = Oh + (size_t)(q0w + 4*g + reg) * D + r;
        #pragma unroll
        for (int dt = 0; dt < 8; ++dt) orow[dt*16] = acc_o[dt][reg] * iv;
    }
}

extern "C" void kernel_launch(void* const* d_in, const int* in_sizes, int n_in,
                              void* d_out, int out_size, void* d_ws, size_t ws_size,
                              hipStream_t stream) {
    const float* Q = (const float*)d_in[0];
    const float* K = (const float*)d_in[1];
    const float* V = (const float*)d_in[2];
    float* O = (float*)d_out;

    const size_t need = (size_t)32 * S * D * 2 * 2;   // Kb + Vt, bf16, 32 heads
    if (ws_size >= need) {
        __bf16* Kb = (__bf16*)d_ws;
        __bf16* Vt = Kb + (size_t)32 * S * D;
        pack_kv<<<dim3(32, 32, 2), 256, 0, stream>>>(K, V, Kb, Vt);
        attn_core<<<dim3(32, 16), 256, 0, stream>>>(Q, Kb, Vt, O);
    } else {
        attn_fallback<<<dim3(32, 32), 256, 0, stream>>>(Q, K, V, O);
    }
}

// Round 15
// 104.233 us; speedup vs baseline: 2.6443x; 2.6443x over previous
//
#include <hip/hip_runtime.h>
#include <hip/hip_bf16.h>
#include <stdint.h>

typedef __bf16  bf16x8 __attribute__((ext_vector_type(8)));
typedef __bf16  bf16x4 __attribute__((ext_vector_type(4)));
typedef float   f32x4  __attribute__((ext_vector_type(4)));
typedef uint32_t u32x4 __attribute__((ext_vector_type(4)));

#define S     2048
#define D     128
#define KVBLK 32
#define NQT   32            // q-tiles of 64
#define THR2  11.5415603f   // 8 * log2(e)

__device__ __forceinline__ uint32_t cvt_pk(float lo, float hi2) {
    uint32_t u;
    asm("v_cvt_pk_bf16_f32 %0, %1, %2" : "=v"(u) : "v"(lo), "v"(hi2));
    return u;
}
__device__ __forceinline__ float exp2fast(float x) {
    return __builtin_amdgcn_exp2f(x);
}
// async global->LDS, 16B per lane; lds base is wave-uniform, HW adds lane*16
__device__ __forceinline__ void gl2lds16(const void* g, void* l) {
    __builtin_amdgcn_global_load_lds(
        (const __attribute__((address_space(1))) void*)g,
        (__attribute__((address_space(3))) void*)l, 16, 0, 0);
}

// ============ kernel A: pack K, V^T to bf16 in pre-swizzled LDS image ========
// per (bh, 32-kv tile): 8KB K block + 8KB Vt block
__global__ __launch_bounds__(256) void pack_kv(
    const float* __restrict__ K, const float* __restrict__ V,
    __bf16* __restrict__ Kp, __bf16* __restrict__ Vp)
{
    const int bh = blockIdx.x, t = blockIdx.y;
    const int tid = threadIdx.x;
    const int kv0 = t * KVBLK;

    // ---- K: direct convert into swizzled image ----
    {
        const float* src = K + ((size_t)bh * S + kv0) * D;
        char* dst = (char*)Kp + ((size_t)(bh * 64 + t)) * 8192;
        #pragma unroll
        for (int cc = 0; cc < 2; ++cc) {
            const int c = cc * 256 + tid;       // 0..511 16B chunks
            const int row = c >> 4, col16 = c & 15;
            const float4 a = *reinterpret_cast<const float4*>(src + row * D + col16 * 8);
            const float4 b = *reinterpret_cast<const float4*>(src + row * D + col16 * 8 + 4);
            bf16x8 o;
            o[0]=(__bf16)a.x; o[1]=(__bf16)a.y; o[2]=(__bf16)a.z; o[3]=(__bf16)a.w;
            o[4]=(__bf16)b.x; o[5]=(__bf16)b.y; o[6]=(__bf16)b.z; o[7]=(__bf16)b.w;
            *reinterpret_cast<bf16x8*>(
                dst + row * 256 + ((col16 * 16) ^ ((row & 15) << 4))) = o;
        }
    }

    // ---- V: transpose via LDS, write swizzled Vt image ----
    __shared__ __bf16 lds[32][136];             // 272B stride
    {
        const float* src = V + ((size_t)bh * S + kv0) * D;
        #pragma unroll
        for (int it = 0; it < 4; ++it) {
            const int id = it * 256 + tid;      // 0..1023 float4
            const int row = id >> 5, c4 = id & 31;
            float4 v = *reinterpret_cast<const float4*>(src + row * D + c4 * 4);
            bf16x4 b4;
            b4[0]=(__bf16)v.x; b4[1]=(__bf16)v.y; b4[2]=(__bf16)v.z; b4[3]=(__bf16)v.w;
            *reinterpret_cast<bf16x4*>(&lds[row][c4 * 4]) = b4;
        }
    }
    __syncthreads();
    {
        char* dst = (char*)Vp + ((size_t)(bh * 64 + t)) * 8192;
        #pragma unroll
        for (int cc = 0; cc < 2; ++cc) {
            const int c = cc * 256 + tid;       // 0..511
            const int d = c >> 2, c8 = c & 3;   // kv chunk c8*8..+7
            bf16x8 o;
            #pragma unroll
            for (int k = 0; k < 8; ++k) o[k] = lds[c8 * 8 + k][d];
            const int addr = (d >> 1) * 128 +
                ((((d & 1) << 6) + c8 * 16) ^ (((d >> 1) & 3) << 4));
            *reinterpret_cast<bf16x8*>(dst + addr) = o;
        }
    }
}

// ============ kernel B: attention core, global_load_lds staging =============
__global__ __launch_bounds__(256, 4) void attn_fwd(
    const float* __restrict__ Q, const __bf16* __restrict__ Kp,
    const __bf16* __restrict__ Vp, float* __restrict__ O)
{
    const int bh = blockIdx.x;              // heads fastest
    const int qt = (NQT - 1) - blockIdx.y;  // LPT: longest first
    const int tid  = threadIdx.x;
    const int w    = tid >> 6;
    const int lane = tid & 63;
    const int r    = lane & 15;
    const int g    = lane >> 4;

    const float* Qh = Q + (size_t)bh * S * D;
    float*       Oh = O + (size_t)bh * S * D;
    const char*  Kbase = (const char*)Kp + (size_t)bh * 64 * 8192;
    const char*  Vbase = (const char*)Vp + (size_t)bh * 64 * 8192;

    const int q0w = qt * 64 + w * 16;       // wave's first q row

    __shared__ __align__(16) __bf16 K_sh[2][KVBLK * D];   // 8KB each
    __shared__ __align__(16) __bf16 V_sh[2][D * KVBLK];   // 8KB each

    const float scale = 0.08838834764831845f * 1.4426950408889634f;

    // ---- Q fragments (B operand): col=q0w+r, k = kb*32 + g*8 + e ----
    bf16x8 qfrag[4];
    {
        const float4* qp = reinterpret_cast<const float4*>(
            Qh + (size_t)(q0w + r) * D + g * 8);
        #pragma unroll
        for (int kb = 0; kb < 4; ++kb) {
            float4 a = qp[kb*8 + 0];
            float4 b = qp[kb*8 + 1];
            a.x*=scale; a.y*=scale; a.z*=scale; a.w*=scale;
            b.x*=scale; b.y*=scale; b.z*=scale; b.w*=scale;
            bf16x8 f;
            f[0]=(__bf16)a.x; f[1]=(__bf16)a.y; f[2]=(__bf16)a.z; f[3]=(__bf16)a.w;
            f[4]=(__bf16)b.x; f[5]=(__bf16)b.y; f[6]=(__bf16)b.z; f[7]=(__bf16)b.w;
            qfrag[kb] = f;
        }
    }

    // async stage of tile t into buffer buf (4 x 16B per thread)
    auto STAGE = [&](int buf, int t) {
        const char* ks = Kbase + (size_t)t * 8192 + w * 1024 + lane * 16;
        const char* vs = Vbase + (size_t)t * 8192 + w * 1024 + lane * 16;
        char* kd = (char*)(&K_sh[buf][0]) + w * 1024;   // wave-uniform base
        char* vd = (char*)(&V_sh[buf][0]) + w * 1024;
        gl2lds16(ks,        kd);
        gl2lds16(ks + 4096, kd + 4096);
        gl2lds16(vs,        vd);
        gl2lds16(vs + 4096, vd + 4096);
    };

    const f32x4 vzero = {0.f, 0.f, 0.f, 0.f};
    f32x4 acc_o[8];
    #pragma unroll
    for (int i = 0; i < 8; ++i) acc_o[i] = vzero;
    float m_run = -1e30f, l_run = 0.f;

    const int n_iter = 2 * qt + 2;           // tiles 0 .. n_iter-1
    const int my_max = (q0w + 15) >> 5;      // wave's last live tile

    STAGE(0, 0);
    __syncthreads();
    int cur = 0;

    for (int t = 0; t < n_iter; ++t) {
        if (t + 1 < n_iter) STAGE(cur ^ 1, t + 1);   // async, drains at barrier

        if (t <= my_max) {
            const int kv0 = t * KVBLK;
            char* Kb = reinterpret_cast<char*>(&K_sh[cur][0]);
            char* Vb = reinterpret_cast<char*>(&V_sh[cur][0]);
            const bool alive1 = (kv0 + 16 <= q0w + 15);

            // ---- swapped QK^T: S^T[kv][q]; lane owns q = q0w + r ----
            f32x4 st[2] = {vzero, vzero};
            __builtin_amdgcn_s_setprio(1);
            #pragma unroll
            for (int tt = 0; tt < 2; ++tt) {
                if (tt == 1 && !alive1) break;
                const int row = tt * 16 + r;
                #pragma unroll
                for (int kb = 0; kb < 4; ++kb) {
                    bf16x8 kf = *reinterpret_cast<const bf16x8*>(
                        Kb + row * 256 + ((kb*64 + g*16) ^ ((row & 15) << 4)));
                    st[tt] = __builtin_amdgcn_mfma_f32_16x16x32_bf16(
                        kf, qfrag[kb], st[tt], 0, 0, 0);
                }
            }
            __builtin_amdgcn_s_setprio(0);

            // ---- mask + in-register online softmax (exp2 domain) ----
            const int q = q0w + r;
            float pmax = -1e30f;
            #pragma unroll
            for (int tt = 0; tt < 2; ++tt) {
                if (tt == 1 && !alive1) break;
                if (kv0 + tt*16 + 15 > q0w) {
                    #pragma unroll
                    for (int jj = 0; jj < 4; ++jj)
                        if (kv0 + tt*16 + 4*g + jj > q) st[tt][jj] = -1e30f;
                }
                #pragma unroll
                for (int jj = 0; jj < 4; ++jj) pmax = fmaxf(pmax, st[tt][jj]);
            }
            pmax = fmaxf(pmax, __shfl_xor(pmax, 16));
            pmax = fmaxf(pmax, __shfl_xor(pmax, 32));

            if (__any(pmax > m_run + THR2)) {        // rare (defer-max)
                const float m_new = fmaxf(m_run, pmax);
                const float corr  = exp2fast(m_run - m_new);
                l_run *= corr; m_run = m_new;
                #pragma unroll
                for (int reg = 0; reg < 4; ++reg) {
                    const float cr = __shfl(corr, 4*g + reg);
                    #pragma unroll
                    for (int dt = 0; dt < 8; ++dt) acc_o[dt][reg] *= cr;
                }
            }

            float rowsum = 0.f;
            #pragma unroll
            for (int tt = 0; tt < 2; ++tt) {
                if (tt == 1 && !alive1) break;
                #pragma unroll
                for (int jj = 0; jj < 4; ++jj) {
                    const float p = exp2fast(st[tt][jj] - m_run);
                    st[tt][jj] = p;
                    rowsum += p;
                }
            }
            rowsum += __shfl_xor(rowsum, 16);
            rowsum += __shfl_xor(rowsum, 32);
            l_run += rowsum;

            // ---- P redistribute to A-fragment (k = g*8 + e) ----
            const uint32_t p00 = cvt_pk(st[0][0], st[0][1]);
            const uint32_t p01 = cvt_pk(st[0][2], st[0][3]);
            const uint32_t p10 = alive1 ? cvt_pk(st[1][0], st[1][1]) : 0u;
            const uint32_t p11 = alive1 ? cvt_pk(st[1][2], st[1][3]) : 0u;
            const int sA = r + ((2 * (g & 1)) << 4);
            const int sB = r + ((2 * (g & 1) + 1) << 4);
            u32x4 words;
            {
                const uint32_t lo0 = (uint32_t)__shfl((int)p00, sA);
                const uint32_t hi0 = (uint32_t)__shfl((int)p10, sA);
                const uint32_t lo1 = (uint32_t)__shfl((int)p01, sA);
                const uint32_t hi1 = (uint32_t)__shfl((int)p11, sA);
                const uint32_t lo2 = (uint32_t)__shfl((int)p00, sB);
                const uint32_t hi2 = (uint32_t)__shfl((int)p10, sB);
                const uint32_t lo3 = (uint32_t)__shfl((int)p01, sB);
                const uint32_t hi3 = (uint32_t)__shfl((int)p11, sB);
                words[0] = (g & 2) ? hi0 : lo0;
                words[1] = (g & 2) ? hi1 : lo1;
                words[2] = (g & 2) ? hi2 : lo2;
                words[3] = (g & 2) ? hi3 : lo3;
            }
            const bf16x8 pa = __builtin_bit_cast(bf16x8, words);

            // ---- PV: B = Vt[d = dt*16 + r][kv = g*8 ..] ----
            __builtin_amdgcn_s_setprio(1);
            #pragma unroll
            for (int dt = 0; dt < 8; ++dt) {
                const int d = dt * 16 + r;
                const int byte = (d >> 1) * 128 +
                    ((((d & 1) << 6) + (g << 4)) ^ (((d >> 1) & 3) << 4));
                bf16x8 vf = *reinterpret_cast<const bf16x8*>(Vb + byte);
                acc_o[dt] = __builtin_amdgcn_mfma_f32_16x16x32_bf16(
                    pa, vf, acc_o[dt], 0, 0, 0);
            }
            __builtin_amdgcn_s_setprio(0);
        }

        __syncthreads();    // drains gload_lds (vmcnt) + publishes buf[cur^1]
        cur ^= 1;
    }

    // ---- epilogue: O[q0w + 4g + reg][dt*16 + r] = acc / l ----
    const float inv = 1.0f / l_run;
    #pragma unroll
    for (int reg = 0; reg < 4; ++reg) {
        const float iv = __shfl(inv, 4*g + reg);
        float* orow = Oh + (size_t)(q0w + 4*g + reg) * D + r;
        #pragma unroll
        for (int dt = 0; dt < 8; ++dt)
            orow[dt * 16] = acc_o[dt][reg] * iv;
    }
}

extern "C" void kernel_launch(void* const* d_in, const int* in_sizes, int n_in,
                              void* d_out, int out_size, void* d_ws, size_t ws_size,
                              hipStream_t stream) {
    const float* Q = (const float*)d_in[0];
    const float* K = (const float*)d_in[1];
    const float* V = (const float*)d_in[2];
    float* O = (float*)d_out;

    __bf16* Kp = (__bf16*)d_ws;                       // 16MB
    __bf16* Vp = Kp + (size_t)32 * S * D;             // 16MB

    pack_kv<<<dim3(32, 64), 256, 0, stream>>>(K, V, Kp, Vp);
    attn_fwd<<<dim3(32, NQT), 256, 0, stream>>>(Q, Kp, Vp, O);
}